// Round 1
// baseline (115.830 us; speedup 1.0000x reference)
//
#include <hip/hip_runtime.h>

#define NATOMS 8192
#define NMOLS  256
#define APM    32
#define EPM    61
#define D      64
#define FIN    16
#define S      65   // padded LDS row stride (floats): bank = (row+ k)%32 -> 2-way, free

__global__ __launch_bounds__(256) void graphnet_kernel(
    const float* __restrict__ atoms,   // (8192,16)
    const float* __restrict__ adj,     // (8192,8192)
    const int*   __restrict__ left,    // (15616)
    const int*   __restrict__ right,   // (15616)
    const float* __restrict__ Wfe, const float* __restrict__ bfe,
    const float* __restrict__ Wfv, const float* __restrict__ bfv,
    const float* __restrict__ Wfu, const float* __restrict__ bfu,
    const float* __restrict__ Wpe, const float* __restrict__ bpe,
    const float* __restrict__ Wpv, const float* __restrict__ bpv,
    const float* __restrict__ Wpu, const float* __restrict__ bpu,
    float* __restrict__ out)           // (15616,64)
{
    __shared__ float he [EPM][S];
    __shared__ float he0[EPM][S];
    __shared__ float hv [APM][S];
    __shared__ float hv0[APM][S];
    __shared__ float hbi[APM][S];      // h_e_bar_i scatter result
    __shared__ float hu[D], hu0[D];
    __shared__ float apm_s[FIN];
    __shared__ float bo_s[EPM];
    __shared__ float part [4][D];      // phi_u partials / hebar partials
    __shared__ float part2[4][D];      // hvbar partials
    __shared__ float hebar[D], hvbar[D];
    __shared__ int   lloc[EPM], rloc[EPM];
    __shared__ int   inc[APM][4], deg[APM];

    const int tid  = threadIdx.x;
    const int lane = tid & 63;
    const int wv   = tid >> 6;
    const int m    = blockIdx.x;
    // wave-uniform column base -> forces scalar (s_load) weight fetches
    const int cb   = __builtin_amdgcn_readfirstlane(wv) * 16;

    // ---------------- init: indices, bond orders, atoms_per_mol ----------------
    if (tid < EPM) {
        int gl = left [m*EPM + tid];
        int gr = right[m*EPM + tid];
        lloc[tid] = gl - m*APM;
        rloc[tid] = gr - m*APM;
        bo_s[tid] = adj[(size_t)gl * NATOMS + gr];
    }
    if (tid < FIN) {
        float s = 0.f;
        for (int a = 0; a < APM; ++a) s += atoms[(m*APM + a)*FIN + tid];
        apm_s[tid] = s;
    }
    __syncthreads();

    // deterministic incidence lists (no atomics -> bitwise-stable across replays)
    if (tid < APM) {
        int d = 0;
        for (int e = 0; e < EPM; ++e) {
            if (lloc[e] == tid) inc[tid][d++] = e;
            if (rloc[e] == tid) inc[tid][d++] = e;
        }
        deg[tid] = d;
    }

    // h_v = tanh(atoms @ W_fv + b_fv)   (32x64, K=16)
    for (int i = 0; i < 8; ++i) {
        int idx = tid + 256*i;
        int a = idx >> 6, c = idx & 63;      // a is wave-uniform
        float acc = bfv[c];
        #pragma unroll
        for (int f = 0; f < FIN; ++f)
            acc += atoms[(m*APM + a)*FIN + f] * Wfv[f*D + c];
        float t = tanhf(acc);
        hv[a][c] = t; hv0[a][c] = t;
    }
    // h_u = tanh(atoms_per_mol @ W_fu + b_fu)   (1x64, K=16)
    if (tid < D) {
        float acc = bfu[tid];
        #pragma unroll
        for (int f = 0; f < FIN; ++f) acc += apm_s[f] * Wfu[f*D + tid];
        float t = tanhf(acc);
        hu[tid] = t; hu0[tid] = t;
    }
    // h_e = tanh(bond_orders[:,None] @ W_fe + b_fe)   (61x64, K=1)
    for (int i = 0; i < 16; ++i) {
        int idx = tid + 256*i;
        int e = idx >> 6, c = idx & 63;      // e wave-uniform
        if (e < EPM) {
            float t = tanhf(bo_s[e] * Wfe[c] + bfe[c]);
            he[e][c] = t; he0[e][c] = t;
        }
    }
    __syncthreads();

    // ---------------- 3 message-passing iterations ----------------
    for (int it = 0; it < 3; ++it) {
        // ---- phi_e:  tanh(he@W1 + he0@W2 + hv[l]@W3 + hv[r]@W4 + ue*W5 + b) ----
        // ue = sum_f hu[f]  (per-mol scalar), computed redundantly per wave
        float uev = hu[lane];
        #pragma unroll
        for (int off = 32; off; off >>= 1) uev += __shfl_xor(uev, off, 64);

        const int row = lane;                 // edge row (61 valid of 64)
        const int rr  = (row < EPM) ? row : 0;
        const int ll  = lloc[rr];
        const int rl  = rloc[rr];

        float acc[16];
        #pragma unroll
        for (int c = 0; c < 16; ++c) acc[c] = 0.f;

        #pragma unroll 4
        for (int k = 0; k < D; ++k) {
            float x1 = he [rr][k];
            float x2 = he0[rr][k];
            float x3 = hv [ll][k];
            float x4 = hv [rl][k];
            const float* w1 = Wpe + (      k)*D + cb;
            const float* w2 = Wpe + (  D + k)*D + cb;
            const float* w3 = Wpe + (2*D + k)*D + cb;
            const float* w4 = Wpe + (3*D + k)*D + cb;
            #pragma unroll
            for (int c = 0; c < 16; ++c)
                acc[c] += x1*w1[c] + x2*w2[c] + x3*w3[c] + x4*w4[c];
        }
        float outv[16];
        #pragma unroll
        for (int c = 0; c < 16; ++c)
            outv[c] = tanhf(acc[c] + bpe[cb + c] + uev * Wpe[4*D*D + cb + c]);

        __syncthreads();                      // old he fully consumed by all waves
        if (row < EPM) {
            #pragma unroll
            for (int c = 0; c < 16; ++c) he[row][cb + c] = outv[c];
            if (it == 2) {
                #pragma unroll
                for (int c = 0; c < 16; ++c)
                    out[(size_t)(m*EPM + row)*D + cb + c] = outv[c];
            }
        }
        __syncthreads();
        if (it == 2) break;                   // output is h_e after 3rd phi_e

        // ---- rho_e_v: h_e_bar_i[a] = sum of incident (new) edge features ----
        for (int i = 0; i < 8; ++i) {
            int idx = tid + 256*i;
            int a = idx >> 6, c = idx & 63;   // a wave-uniform -> no divergence
            float s = 0.f;
            int dg = deg[a];
            for (int j = 0; j < dg; ++j) s += he[inc[a][j]][c];
            hbi[a][c] = s;
        }
        // hebar partials (segment-sum of new h_e over edges)
        {
            float s = 0.f;
            int r1 = min(wv*16 + 16, EPM);
            for (int r = wv*16; r < r1; ++r) s += he[r][lane];
            part[wv][lane] = s;
        }
        __syncthreads();

        // ---- phi_v: tanh(hv@V1 + hv0@V2 + hbi@V3 + hu@V4 + b) ----
        const int a = lane & 31;              // lanes 32..63 duplicate (stores masked)
        #pragma unroll
        for (int c = 0; c < 16; ++c) acc[c] = 0.f;

        #pragma unroll 4
        for (int k = 0; k < D; ++k) {
            float x1 = hv [a][k];
            float x2 = hv0[a][k];
            float x3 = hbi[a][k];
            float x4 = hu[k];
            const float* w1 = Wpv + (      k)*D + cb;
            const float* w2 = Wpv + (  D + k)*D + cb;
            const float* w3 = Wpv + (2*D + k)*D + cb;
            const float* w4 = Wpv + (3*D + k)*D + cb;
            #pragma unroll
            for (int c = 0; c < 16; ++c)
                acc[c] += x1*w1[c] + x2*w2[c] + x3*w3[c] + x4*w4[c];
        }
        #pragma unroll
        for (int c = 0; c < 16; ++c)
            outv[c] = tanhf(acc[c] + bpv[cb + c]);

        __syncthreads();                      // old hv fully consumed
        if (lane < APM) {
            #pragma unroll
            for (int c = 0; c < 16; ++c) hv[a][cb + c] = outv[c];
        }
        __syncthreads();

        // hvbar partials (segment-sum of new h_v)
        {
            float s = 0.f;
            for (int r = wv*8; r < wv*8 + 8; ++r) s += hv[r][lane];
            part2[wv][lane] = s;
        }
        __syncthreads();
        if (tid < D) {
            hebar[tid] = part[0][tid] + part[1][tid] + part[2][tid] + part[3][tid];
        } else if (tid < 2*D) {
            int c = tid - D;
            hvbar[c] = part2[0][c] + part2[1][c] + part2[2][c] + part2[3][c];
        }
        __syncthreads();

        // ---- phi_u: tanh(hu@U1 + hu0@U2 + hebar@U3 + hvbar@U4 + b) ----
        {
            const float* src = (wv == 0) ? hu : (wv == 1) ? hu0
                             : (wv == 2) ? hebar : hvbar;
            float s = 0.f;
            #pragma unroll 4
            for (int kk = 0; kk < D; ++kk)
                s += src[kk] * Wpu[(wv*D + kk)*D + lane];
            part[wv][lane] = s;               // part free again (hebar finalized)
        }
        __syncthreads();
        if (tid < D) {
            hu[tid] = tanhf(part[0][tid] + part[1][tid] + part[2][tid]
                          + part[3][tid] + bpu[tid]);
        }
        __syncthreads();
    }
}

extern "C" void kernel_launch(void* const* d_in, const int* in_sizes, int n_in,
                              void* d_out, int out_size, void* d_ws, size_t ws_size,
                              hipStream_t stream) {
    const float* atoms = (const float*)d_in[0];
    const float* adj   = (const float*)d_in[1];
    const int*   left  = (const int*)  d_in[2];
    const int*   right = (const int*)  d_in[3];
    // d_in[4] atom_in_mol, d_in[5] bond_in_mol: one-hot masks, derivable (idx/32) -> unused
    const float* Wfe = (const float*)d_in[6];
    const float* bfe = (const float*)d_in[7];
    const float* Wfv = (const float*)d_in[8];
    const float* bfv = (const float*)d_in[9];
    const float* Wfu = (const float*)d_in[10];
    const float* bfu = (const float*)d_in[11];
    const float* Wpe = (const float*)d_in[12];
    const float* bpe = (const float*)d_in[13];
    const float* Wpv = (const float*)d_in[14];
    const float* bpv = (const float*)d_in[15];
    const float* Wpu = (const float*)d_in[16];
    const float* bpu = (const float*)d_in[17];

    graphnet_kernel<<<dim3(NMOLS), dim3(256), 0, stream>>>(
        atoms, adj, left, right,
        Wfe, bfe, Wfv, bfv, Wfu, bfu,
        Wpe, bpe, Wpv, bpv, Wpu, bpu,
        (float*)d_out);
}

// Round 3
// 59.643 us; speedup vs baseline: 1.9420x; 1.9420x over previous
//
#include <hip/hip_runtime.h>

#define NATOMS 8192
#define NMOLS  256
#define APM    32
#define EPM    61
#define D      64
#define FIN    16
#define SE     72   // bf16 elems per LDS state row (144B = 9*16B)

typedef __bf16 bf16x8 __attribute__((ext_vector_type(8)));
typedef float  f32x4  __attribute__((ext_vector_type(4)));

#define MFMA_BF16(a, b, c) __builtin_amdgcn_mfma_f32_16x16x32_bf16((a), (b), (c), 0, 0, 0)

__device__ __forceinline__ ushort f2bf(float x) {   // RNE f32 -> bf16
    uint u = __float_as_uint(x);
    u += 0x7fffu + ((u >> 16) & 1u);
    return (ushort)(u >> 16);
}
__device__ __forceinline__ float bf2f(ushort h) {
    return __uint_as_float(((uint)h) << 16);
}
// split x into hi + lo bf16 pair: hi+lo represents x to ~2^-18 relative
__device__ __forceinline__ void split2(float x, ushort& h, ushort& l) {
    ushort hh = f2bf(x);
    h = hh;
    l = f2bf(x - bf2f(hh));
}

union FragU { ushort u[8]; bf16x8 v; };

__global__ __launch_bounds__(512) void graphnet_kernel(
    const float* __restrict__ atoms,   // (8192,16)
    const float* __restrict__ adj,     // (8192,8192)
    const int*   __restrict__ left,    // (15616)
    const int*   __restrict__ right,   // (15616)
    const float* __restrict__ Wfe, const float* __restrict__ bfe,
    const float* __restrict__ Wfv, const float* __restrict__ bfv,
    const float* __restrict__ Wfu, const float* __restrict__ bfu,
    const float* __restrict__ Wpe, const float* __restrict__ bpe,
    const float* __restrict__ Wpv, const float* __restrict__ bpv,
    const float* __restrict__ Wpu, const float* __restrict__ bpu,
    float* __restrict__ out)           // (15616,64) fp32
{
    __shared__ __align__(16) ushort heH [64 * SE], heL [64 * SE];   // rows 61-63 zero
    __shared__ __align__(16) ushort he0H[64 * SE], he0L[64 * SE];
    __shared__ __align__(16) ushort hvH [APM * SE], hvL [APM * SE];
    __shared__ __align__(16) ushort hv0H[APM * SE], hv0L[APM * SE];
    __shared__ __align__(16) ushort hbiH[APM * SE], hbiL[APM * SE];
    __shared__ __align__(16) ushort huH[D], huL[D];
    __shared__ float hu[D], hu0[D];
    __shared__ float atoms_s[APM * FIN];
    __shared__ float apm_s[FIN];
    __shared__ float bo_s[EPM];
    __shared__ float parte[4][D];      // hebar partials per edge M-tile
    __shared__ float part2[2][D];      // hvbar partials per atom M-tile
    __shared__ float hebar[D];
    __shared__ float phiu_part[4][D];
    __shared__ int   lloc[EPM], rloc[EPM];
    __shared__ int   inc[APM][4], deg[APM];

    const int tid  = threadIdx.x;
    const int lane = tid & 63;
    const int w    = tid >> 6;                 // wave 0..7
    const int nt   = w & 3;                    // N-tile (16-col slice)
    const int mt2  = w >> 2;                   // 0..1
    const int cb   = __builtin_amdgcn_readfirstlane(nt) * 16;
    const int lr   = lane & 15;                // A-row-in-tile / C,D-col-in-tile
    const int kb   = lane >> 4;                // k-block 0..3
    const int m    = blockIdx.x;

    // ---------------- stage inputs ----------------
    if (tid < EPM) {
        int gl = left [m * EPM + tid];
        int gr = right[m * EPM + tid];
        lloc[tid] = gl - m * APM;
        rloc[tid] = gr - m * APM;
        bo_s[tid] = adj[(size_t)gl * NATOMS + gr];
    }
    if (tid < APM * FIN) atoms_s[tid] = atoms[(size_t)m * (APM * FIN) + tid];

    // ---------------- weight fragments hi/lo (once, reused all iters) ----------------
    // B-frag step s: lane holds W[s*32 + kb*8 + j][cb + lr]
    FragU feH[8], feL[8], fvH[8], fvL[8];
    #pragma unroll
    for (int s = 0; s < 8; ++s) {
        #pragma unroll
        for (int j = 0; j < 8; ++j) {
            split2(Wpe[(s * 32 + kb * 8 + j) * D + cb + lr], feH[s].u[j], feL[s].u[j]);
            split2(Wpv[(s * 32 + kb * 8 + j) * D + cb + lr], fvH[s].u[j], fvL[s].u[j]);
        }
    }
    const float bias_e = bpe[cb + lr];
    const float w5_e   = Wpe[4 * D * D + cb + lr];   // u_e column (K row 256)
    const float bias_v = bpv[cb + lr];

    __syncthreads();

    // incidence lists (deterministic, no atomics)
    if (tid < APM) {
        int dg = 0;
        for (int e = 0; e < EPM; ++e) {
            if (lloc[e] == tid) inc[tid][dg++] = e;
            if (rloc[e] == tid) inc[tid][dg++] = e;
        }
        deg[tid] = dg;
    }
    if (tid < FIN) {
        float s = 0.f;
        for (int a = 0; a < APM; ++a) s += atoms_s[a * FIN + tid];
        apm_s[tid] = s;
    }
    // h_v = tanh(atoms @ W_fv + b)   32x64
    #pragma unroll
    for (int i = 0; i < 4; ++i) {
        int idx = tid + 512 * i;               // 0..2047
        int a = idx >> 6, c = idx & 63;
        float acc = bfv[c];
        #pragma unroll
        for (int f = 0; f < FIN; ++f) acc += atoms_s[a * FIN + f] * Wfv[f * D + c];
        float t = tanhf(acc);
        ushort h, l; split2(t, h, l);
        hvH[a * SE + c] = h; hvL[a * SE + c] = l;
        hv0H[a * SE + c] = h; hv0L[a * SE + c] = l;
    }
    // h_e = tanh(bo * W_fe + b)   61x64 (+ zero pad rows 61-63)
    #pragma unroll
    for (int i = 0; i < 8; ++i) {
        int idx = tid + 512 * i;               // 0..4095
        int e = idx >> 6, c = idx & 63;
        float t = 0.f;
        if (e < EPM) t = tanhf(bo_s[e] * Wfe[c] + bfe[c]);
        ushort h, l; split2(t, h, l);
        heH[e * SE + c] = h; heL[e * SE + c] = l;
        he0H[e * SE + c] = h; he0L[e * SE + c] = l;
    }
    __syncthreads();
    // h_u = tanh(atoms_per_mol @ W_fu + b)
    if (tid < D) {
        float acc = bfu[tid];
        #pragma unroll
        for (int f = 0; f < FIN; ++f) acc += apm_s[f] * Wfu[f * D + tid];
        float t = tanhf(acc);
        hu[tid] = t; hu0[tid] = t;
        split2(t, huH[tid], huL[tid]);
    }
    __syncthreads();

    const int col = cb + lr;

    // ---------------- 3 message-passing iterations ----------------
    for (int it = 0; it < 3; ++it) {
        // u_e = sum(h_u) per-mol scalar
        float uev = hu[lane];
        #pragma unroll
        for (int off = 32; off; off >>= 1) uev += __shfl_xor(uev, off, 64);

        // ---- phi_e : [he | he0 | hv[l] | hv[r] | u_e] @ Wpe, split-bf16 x3 ----
        const int e0  = mt2 * 16 + lr;         // rows 0..31 (always valid)
        const int e1  = e0 + 32;               // rows 32..63 (61-63 are zero pad)
        const int ec1 = (e1 < EPM) ? e1 : EPM - 1;
        const int la0 = lloc[e0], ra0 = rloc[e0];
        const int la1 = lloc[ec1], ra1 = rloc[ec1];
        const int ofk = kb * 8;

        f32x4 acc0 = {0.f,0.f,0.f,0.f}, acc1 = {0.f,0.f,0.f,0.f};
        #pragma unroll
        for (int s = 0; s < 8; ++s) {
            const ushort *pH0, *pL0, *pH1, *pL1;
            const int o = (s & 1) * 32 + ofk;
            if      (s < 2) { pH0 = &heH [e0*SE];  pL0 = &heL [e0*SE];
                              pH1 = &heH [e1*SE];  pL1 = &heL [e1*SE]; }
            else if (s < 4) { pH0 = &he0H[e0*SE];  pL0 = &he0L[e0*SE];
                              pH1 = &he0H[e1*SE];  pL1 = &he0L[e1*SE]; }
            else if (s < 6) { pH0 = &hvH [la0*SE]; pL0 = &hvL [la0*SE];
                              pH1 = &hvH [la1*SE]; pL1 = &hvL [la1*SE]; }
            else            { pH0 = &hvH [ra0*SE]; pL0 = &hvL [ra0*SE];
                              pH1 = &hvH [ra1*SE]; pL1 = &hvL [ra1*SE]; }
            bf16x8 ah0 = *(const bf16x8*)(pH0 + o);
            bf16x8 al0 = *(const bf16x8*)(pL0 + o);
            bf16x8 ah1 = *(const bf16x8*)(pH1 + o);
            bf16x8 al1 = *(const bf16x8*)(pL1 + o);
            acc0 = MFMA_BF16(ah0, feH[s].v, acc0);
            acc1 = MFMA_BF16(ah1, feH[s].v, acc1);
            acc0 = MFMA_BF16(al0, feH[s].v, acc0);
            acc1 = MFMA_BF16(al1, feH[s].v, acc1);
            acc0 = MFMA_BF16(ah0, feL[s].v, acc0);
            acc1 = MFMA_BF16(ah1, feL[s].v, acc1);
        }
        // epilogue.  D layout: row=kb*4+r (in tile), col=lr
        float out0[4], out1[4]; float ps0 = 0.f, ps1 = 0.f;
        #pragma unroll
        for (int r = 0; r < 4; ++r) {
            float t0 = tanhf(acc0[r] + bias_e + uev * w5_e);
            float t1 = tanhf(acc1[r] + bias_e + uev * w5_e);
            out0[r] = t0; out1[r] = t1;
            ps0 += t0;                                        // rows < 32: all valid
            if (32 + mt2 * 16 + kb * 4 + r < EPM) ps1 += t1;  // hebar partial
        }
        if (it < 2) {
            ps0 += __shfl_xor(ps0, 16, 64); ps0 += __shfl_xor(ps0, 32, 64);
            ps1 += __shfl_xor(ps1, 16, 64); ps1 += __shfl_xor(ps1, 32, 64);
        }
        __syncthreads();                       // all he/hv A-reads done
        #pragma unroll
        for (int r = 0; r < 4; ++r) {
            int g0 = mt2 * 16 + kb * 4 + r;
            split2(out0[r], heH[g0 * SE + col], heL[g0 * SE + col]);
            if (it == 2) out[((size_t)(m * EPM + g0)) * D + col] = out0[r];
            int g1 = g0 + 32;
            if (g1 < EPM) {
                split2(out1[r], heH[g1 * SE + col], heL[g1 * SE + col]);
                if (it == 2) out[((size_t)(m * EPM + g1)) * D + col] = out1[r];
            }
        }
        if (it < 2 && kb == 0) { parte[mt2][col] = ps0; parte[2 + mt2][col] = ps1; }
        if (it == 2) break;                    // output = h_e after 3rd phi_e
        __syncthreads();                       // new he visible

        // ---- rho_e_v: hbi[a] = sum of incident edges (new he, hi+lo) ----
        #pragma unroll
        for (int i = 0; i < 4; ++i) {
            int idx = tid + 512 * i;           // 0..2047
            int a = idx >> 6, c = idx & 63;
            float s = 0.f;
            int dg = deg[a];
            for (int j = 0; j < dg; ++j) {
                int e = inc[a][j];
                s += bf2f(heH[e * SE + c]) + bf2f(heL[e * SE + c]);
            }
            split2(s, hbiH[a * SE + c], hbiL[a * SE + c]);
        }
        __syncthreads();

        // ---- phi_v : [hv | hv0 | hbi | hu] @ Wpv, split-bf16 x3 ----
        const int arow = mt2 * 16 + lr;        // atom row 0..31
        f32x4 acc2 = {0.f,0.f,0.f,0.f};
        #pragma unroll
        for (int s = 0; s < 8; ++s) {
            const ushort *pH, *pL;
            const int o = (s & 1) * 32 + ofk;
            if      (s < 2) { pH = &hvH [arow*SE]; pL = &hvL [arow*SE]; }
            else if (s < 4) { pH = &hv0H[arow*SE]; pL = &hv0L[arow*SE]; }
            else if (s < 6) { pH = &hbiH[arow*SE]; pL = &hbiL[arow*SE]; }
            else            { pH = &huH[0];        pL = &huL[0];        }  // broadcast u_v
            bf16x8 ah = *(const bf16x8*)(pH + o);
            bf16x8 al = *(const bf16x8*)(pL + o);
            acc2 = MFMA_BF16(ah, fvH[s].v, acc2);
            acc2 = MFMA_BF16(al, fvH[s].v, acc2);
            acc2 = MFMA_BF16(ah, fvL[s].v, acc2);
        }
        float outv2[4]; float ps2 = 0.f;
        #pragma unroll
        for (int r = 0; r < 4; ++r) {
            float t = tanhf(acc2[r] + bias_v);
            outv2[r] = t; ps2 += t;            // hvbar partial
        }
        ps2 += __shfl_xor(ps2, 16, 64); ps2 += __shfl_xor(ps2, 32, 64);
        __syncthreads();                       // all hv/hbi A-reads done
        #pragma unroll
        for (int r = 0; r < 4; ++r) {
            int g = mt2 * 16 + kb * 4 + r;
            split2(outv2[r], hvH[g * SE + col], hvL[g * SE + col]);
        }
        if (kb == 0) part2[mt2][col] = ps2;
        if (tid < D)                           // hebar reduce (parte ready)
            hebar[tid] = parte[0][tid] + parte[1][tid] + parte[2][tid] + parte[3][tid];
        __syncthreads();

        // ---- phi_u : [hu | hu0 | hebar | hvbar] @ Wpu  (fp32 VALU, waves 0..3) ----
        if (w < 4) {
            float s = 0.f;
            #pragma unroll 4
            for (int k = 0; k < D; ++k) {
                float x = (w == 0) ? hu[k] : (w == 1) ? hu0[k] : (w == 2) ? hebar[k]
                        : (part2[0][k] + part2[1][k]);
                s += x * Wpu[(w * D + k) * D + lane];
            }
            phiu_part[w][lane] = s;
        }
        __syncthreads();
        if (tid < D) {
            float t = tanhf(phiu_part[0][tid] + phiu_part[1][tid] +
                            phiu_part[2][tid] + phiu_part[3][tid] + bpu[tid]);
            hu[tid] = t;
            split2(t, huH[tid], huL[tid]);
        }
        __syncthreads();
    }
}

extern "C" void kernel_launch(void* const* d_in, const int* in_sizes, int n_in,
                              void* d_out, int out_size, void* d_ws, size_t ws_size,
                              hipStream_t stream) {
    const float* atoms = (const float*)d_in[0];
    const float* adj   = (const float*)d_in[1];
    const int*   left  = (const int*)  d_in[2];
    const int*   right = (const int*)  d_in[3];
    // d_in[4]/d_in[5]: one-hot membership masks, derivable (idx/32) -> unused
    const float* Wfe = (const float*)d_in[6];
    const float* bfe = (const float*)d_in[7];
    const float* Wfv = (const float*)d_in[8];
    const float* bfv = (const float*)d_in[9];
    const float* Wfu = (const float*)d_in[10];
    const float* bfu = (const float*)d_in[11];
    const float* Wpe = (const float*)d_in[12];
    const float* bpe = (const float*)d_in[13];
    const float* Wpv = (const float*)d_in[14];
    const float* bpv = (const float*)d_in[15];
    const float* Wpu = (const float*)d_in[16];
    const float* bpu = (const float*)d_in[17];

    graphnet_kernel<<<dim3(NMOLS), dim3(512), 0, stream>>>(
        atoms, adj, left, right,
        Wfe, bfe, Wfv, bfv, Wfu, bfu,
        Wpe, bpe, Wpv, bpv, Wpu, bpu,
        (float*)d_out);
}

// Round 4
// 50.671 us; speedup vs baseline: 2.2859x; 1.1771x over previous
//
#include <hip/hip_runtime.h>

#define NATOMS 8192
#define NMOLS  256
#define APM    32
#define EPM    61
#define D      64
#define FIN    16
#define SE     72   // bf16 elems per LDS state row (144B)

typedef __bf16 bf16x8 __attribute__((ext_vector_type(8)));
typedef float  f32x4  __attribute__((ext_vector_type(4)));

#define MFMA_BF16(a, b, c) __builtin_amdgcn_mfma_f32_16x16x32_bf16((a), (b), (c), 0, 0, 0)

__device__ __forceinline__ ushort f2bf(float x) {   // RNE f32 -> bf16
    uint u = __float_as_uint(x);
    u += 0x7fffu + ((u >> 16) & 1u);
    return (ushort)(u >> 16);
}
__device__ __forceinline__ float bf2f(ushort h) {
    return __uint_as_float(((uint)h) << 16);
}
__device__ __forceinline__ void split2(float x, ushort& h, ushort& l) {
    ushort hh = f2bf(x);
    h = hh;
    l = f2bf(x - bf2f(hh));
}
// tanh(x) = 1 - 2/(exp(2x)+1); exp2-based, handles +-inf saturation naturally
__device__ __forceinline__ float fast_tanh(float x) {
    float e = __builtin_amdgcn_exp2f(x * 2.885390081777926f);   // exp(2x)
    float r = __builtin_amdgcn_rcpf(e + 1.0f);
    return __builtin_fmaf(-2.0f, r, 1.0f);
}

union FragU { ushort u[8]; bf16x8 v; };

__global__ __launch_bounds__(512, 2) void graphnet_kernel(
    const float* __restrict__ atoms,
    const float* __restrict__ adj,
    const int*   __restrict__ left,
    const int*   __restrict__ right,
    const float* __restrict__ Wfe, const float* __restrict__ bfe,
    const float* __restrict__ Wfv, const float* __restrict__ bfv,
    const float* __restrict__ Wfu, const float* __restrict__ bfu,
    const float* __restrict__ Wpe, const float* __restrict__ bpe,
    const float* __restrict__ Wpv, const float* __restrict__ bpv,
    const float* __restrict__ Wpu, const float* __restrict__ bpu,
    float* __restrict__ out)
{
    __shared__ __align__(16) ushort heH[2][64 * SE], heL[2][64 * SE];  // dbuf; rows 61-63 zero
    __shared__ __align__(16) ushort he0H[64 * SE], he0L[64 * SE];
    __shared__ __align__(16) ushort hvH[2][APM * SE], hvL[2][APM * SE];
    __shared__ __align__(16) ushort hv0H[APM * SE], hv0L[APM * SE];
    __shared__ __align__(16) ushort hbiH[APM * SE], hbiL[APM * SE];
    __shared__ __align__(16) ushort huH[D], huL[D];
    __shared__ float huF[D], hu0F[D];
    __shared__ float atoms_s[APM * FIN];
    __shared__ float apm_s[FIN];
    __shared__ float bo_s[EPM];
    __shared__ float parte[4][D];
    __shared__ float part2[2][D];
    __shared__ float hebar[D];
    __shared__ float phiu_part[8][D];
    __shared__ int   lloc[EPM], rloc[EPM];
    __shared__ int   inc[APM][4], deg[APM];

    const int tid  = threadIdx.x;
    const int lane = tid & 63;
    const int w    = tid >> 6;                 // wave 0..7
    const int nt   = w & 3;                    // N-tile (16-col slice)
    const int mt2  = w >> 2;                   // 0..1
    const int cb   = __builtin_amdgcn_readfirstlane(nt) * 16;
    const int lr   = lane & 15;
    const int kb   = lane >> 4;
    const int m    = blockIdx.x;

    // ---------------- stage inputs ----------------
    if (tid < EPM) {
        int gl = left [m * EPM + tid];
        int gr = right[m * EPM + tid];
        lloc[tid] = gl - m * APM;
        rloc[tid] = gr - m * APM;
        bo_s[tid] = adj[(size_t)gl * NATOMS + gr];
    }
    if (tid < APM * FIN) atoms_s[tid] = atoms[(size_t)m * (APM * FIN) + tid];

    // ---------------- weight fragments + phi_u weight slice (registers) ----------------
    FragU feH[8], feL[8], fvH[8], fvL[8];
    #pragma unroll
    for (int s = 0; s < 8; ++s) {
        #pragma unroll
        for (int j = 0; j < 8; ++j) {
            split2(Wpe[(s * 32 + kb * 8 + j) * D + cb + lr], feH[s].u[j], feL[s].u[j]);
            split2(Wpv[(s * 32 + kb * 8 + j) * D + cb + lr], fvH[s].u[j], fvL[s].u[j]);
        }
    }
    float wpu_reg[32];
    #pragma unroll
    for (int kk = 0; kk < 32; ++kk)
        wpu_reg[kk] = Wpu[(w * 32 + kk) * D + lane];
    const float bias_e = bpe[cb + lr];
    const float w5_e   = Wpe[4 * D * D + cb + lr];
    const float bias_v = bpv[cb + lr];
    const float bpu_l  = bpu[lane];

    __syncthreads();                                               // B1

    // incidence lists (deterministic)
    if (tid < APM) {
        int dg = 0;
        for (int e = 0; e < EPM; ++e) {
            if (lloc[e] == tid) inc[tid][dg++] = e;
            if (rloc[e] == tid) inc[tid][dg++] = e;
        }
        deg[tid] = dg;
    }
    if (tid < FIN) {
        float s = 0.f;
        for (int a = 0; a < APM; ++a) s += atoms_s[a * FIN + tid];
        apm_s[tid] = s;
    }
    // h_v init
    #pragma unroll
    for (int i = 0; i < 4; ++i) {
        int idx = tid + 512 * i;               // 0..2047
        int a = idx >> 6, c = idx & 63;
        float acc = bfv[c];
        #pragma unroll
        for (int f = 0; f < FIN; ++f) acc += atoms_s[a * FIN + f] * Wfv[f * D + c];
        float t = fast_tanh(acc);
        ushort h, l; split2(t, h, l);
        hvH[0][a * SE + c] = h; hvL[0][a * SE + c] = l;
        hv0H[a * SE + c] = h;   hv0L[a * SE + c] = l;
    }
    // h_e init (+ zero pad rows in BOTH buffers)
    #pragma unroll
    for (int i = 0; i < 8; ++i) {
        int idx = tid + 512 * i;               // 0..4095
        int e = idx >> 6, c = idx & 63;
        float t = 0.f;
        if (e < EPM) t = fast_tanh(bo_s[e] * Wfe[c] + bfe[c]);
        ushort h, l; split2(t, h, l);
        heH[0][e * SE + c] = h; heL[0][e * SE + c] = l;
        he0H[e * SE + c] = h;   he0L[e * SE + c] = l;
        if (e >= EPM) { heH[1][e * SE + c] = 0; heL[1][e * SE + c] = 0; }
    }
    __syncthreads();                                               // B2

    // h_u: computed redundantly by every wave into registers (lane = feature)
    float hu_val;
    {
        float acc = bfu[lane];
        #pragma unroll
        for (int f = 0; f < FIN; ++f) acc += apm_s[f] * Wfu[f * D + lane];
        hu_val = fast_tanh(acc);
        if (w == 7) {
            huF[lane] = hu_val; hu0F[lane] = hu_val;
            split2(hu_val, huH[lane], huL[lane]);
        }
    }

    const int col = cb + lr;
    const int e0  = mt2 * 16 + lr;
    const int e1  = e0 + 32;
    const int ec1 = (e1 < EPM) ? e1 : EPM - 1;
    const int la0 = lloc[e0],  ra0 = rloc[e0];
    const int la1 = lloc[ec1], ra1 = rloc[ec1];
    const int ofk = kb * 8;
    const int arow = mt2 * 16 + lr;

    int cur = 0;
    // ---------------- 3 message-passing iterations ----------------
    for (int it = 0; it < 3; ++it) {
        // u_e scalar from registers (no LDS, no barrier)
        float uev = hu_val;
        #pragma unroll
        for (int off = 32; off; off >>= 1) uev += __shfl_xor(uev, off, 64);

        // ---- phi_e : 4 independent MFMA chains (Hi x2 rows, Lo x2 rows) ----
        const ushort* heHc = heH[cur]; const ushort* heLc = heL[cur];
        const ushort* hvHc = hvH[cur]; const ushort* hvLc = hvL[cur];

        f32x4 aH0 = {0,0,0,0}, aL0 = {0,0,0,0}, aH1 = {0,0,0,0}, aL1 = {0,0,0,0};
        #pragma unroll
        for (int s = 0; s < 8; ++s) {
            const ushort *pH0, *pL0, *pH1, *pL1;
            const int o = (s & 1) * 32 + ofk;
            if      (s < 2) { pH0 = heHc + e0*SE;  pL0 = heLc + e0*SE;
                              pH1 = heHc + e1*SE;  pL1 = heLc + e1*SE; }
            else if (s < 4) { pH0 = he0H + e0*SE;  pL0 = he0L + e0*SE;
                              pH1 = he0H + e1*SE;  pL1 = he0L + e1*SE; }
            else if (s < 6) { pH0 = hvHc + la0*SE; pL0 = hvLc + la0*SE;
                              pH1 = hvHc + la1*SE; pL1 = hvLc + la1*SE; }
            else            { pH0 = hvHc + ra0*SE; pL0 = hvLc + ra0*SE;
                              pH1 = hvHc + ra1*SE; pL1 = hvLc + ra1*SE; }
            bf16x8 ah0 = *(const bf16x8*)(pH0 + o);
            bf16x8 al0 = *(const bf16x8*)(pL0 + o);
            bf16x8 ah1 = *(const bf16x8*)(pH1 + o);
            bf16x8 al1 = *(const bf16x8*)(pL1 + o);
            aH0 = MFMA_BF16(ah0, feH[s].v, aH0);
            aH1 = MFMA_BF16(ah1, feH[s].v, aH1);
            aL0 = MFMA_BF16(al0, feH[s].v, aL0);
            aL1 = MFMA_BF16(al1, feH[s].v, aL1);
            aL0 = MFMA_BF16(ah0, feL[s].v, aL0);
            aL1 = MFMA_BF16(ah1, feL[s].v, aL1);
        }
        float out0[4], out1[4]; float ps0 = 0.f, ps1 = 0.f;
        #pragma unroll
        for (int r = 0; r < 4; ++r) {
            float t0 = fast_tanh(aH0[r] + aL0[r] + bias_e + uev * w5_e);
            float t1 = fast_tanh(aH1[r] + aL1[r] + bias_e + uev * w5_e);
            out0[r] = t0; out1[r] = t1;
            ps0 += t0;
            if (32 + mt2 * 16 + kb * 4 + r < EPM) ps1 += t1;
        }

        if (it == 2) {                         // final: write output, done
            #pragma unroll
            for (int r = 0; r < 4; ++r) {
                int g0 = mt2 * 16 + kb * 4 + r;
                out[((size_t)(m * EPM + g0)) * D + col] = out0[r];
                int g1 = g0 + 32;
                if (g1 < EPM) out[((size_t)(m * EPM + g1)) * D + col] = out1[r];
            }
            return;
        }

        ps0 += __shfl_xor(ps0, 16, 64); ps0 += __shfl_xor(ps0, 32, 64);
        ps1 += __shfl_xor(ps1, 16, 64); ps1 += __shfl_xor(ps1, 32, 64);

        const int nxt = cur ^ 1;
        #pragma unroll
        for (int r = 0; r < 4; ++r) {
            int g0 = mt2 * 16 + kb * 4 + r;
            split2(out0[r], heH[nxt][g0 * SE + col], heL[nxt][g0 * SE + col]);
            int g1 = g0 + 32;
            if (g1 < EPM)
                split2(out1[r], heH[nxt][g1 * SE + col], heL[nxt][g1 * SE + col]);
        }
        if (kb == 0) { parte[mt2][col] = ps0; parte[2 + mt2][col] = ps1; }
        __syncthreads();                                           // A: new he ready

        // ---- rho_e_v scatter (reads he[nxt]) + hebar reduce ----
        #pragma unroll
        for (int i = 0; i < 4; ++i) {
            int idx = tid + 512 * i;           // 0..2047
            int a = idx >> 6, c = idx & 63;
            float s = 0.f;
            int dg = deg[a];
            for (int j = 0; j < dg; ++j) {
                int e = inc[a][j];
                s += bf2f(heH[nxt][e * SE + c]) + bf2f(heL[nxt][e * SE + c]);
            }
            split2(s, hbiH[a * SE + c], hbiL[a * SE + c]);
        }
        if (tid < D)
            hebar[tid] = parte[0][tid] + parte[1][tid] + parte[2][tid] + parte[3][tid];
        __syncthreads();                                           // B: hbi ready

        // ---- phi_v : 2 chains ----
        f32x4 vH = {0,0,0,0}, vL = {0,0,0,0};
        #pragma unroll
        for (int s = 0; s < 8; ++s) {
            const ushort *pH, *pL;
            const int o = (s & 1) * 32 + ofk;
            if      (s < 2) { pH = hvHc + arow*SE; pL = hvLc + arow*SE; }
            else if (s < 4) { pH = hv0H + arow*SE; pL = hv0L + arow*SE; }
            else if (s < 6) { pH = hbiH + arow*SE; pL = hbiL + arow*SE; }
            else            { pH = huH;            pL = huL;            }
            bf16x8 ah = *(const bf16x8*)(pH + o);
            bf16x8 al = *(const bf16x8*)(pL + o);
            vH = MFMA_BF16(ah, fvH[s].v, vH);
            vL = MFMA_BF16(al, fvH[s].v, vL);
            vL = MFMA_BF16(ah, fvL[s].v, vL);
        }
        float outv2[4]; float ps2 = 0.f;
        #pragma unroll
        for (int r = 0; r < 4; ++r) {
            float t = fast_tanh(vH[r] + vL[r] + bias_v);
            outv2[r] = t; ps2 += t;
        }
        ps2 += __shfl_xor(ps2, 16, 64); ps2 += __shfl_xor(ps2, 32, 64);
        #pragma unroll
        for (int r = 0; r < 4; ++r) {
            int g = mt2 * 16 + kb * 4 + r;
            split2(outv2[r], hvH[nxt][g * SE + col], hvL[nxt][g * SE + col]);
        }
        if (kb == 0) part2[mt2][col] = ps2;
        __syncthreads();                                           // C: part2 ready

        // ---- phi_u partials: wave w owns K rows [w*32, w*32+32) ----
        {
            const int b  = w >> 1;             // source block (wave-uniform)
            const int k0 = (w & 1) * 32;
            float s = 0.f;
            #pragma unroll
            for (int kk = 0; kk < 32; ++kk) {
                int k = k0 + kk;
                float x = (b == 0) ? huF[k] : (b == 1) ? hu0F[k]
                        : (b == 2) ? hebar[k] : (part2[0][k] + part2[1][k]);
                s += x * wpu_reg[kk];
            }
            phiu_part[w][lane] = s;
        }
        __syncthreads();                                           // D: phiu ready

        // finalize h_u redundantly in registers (all waves)
        {
            float t = bpu_l;
            #pragma unroll
            for (int w8 = 0; w8 < 8; ++w8) t += phiu_part[w8][lane];
            hu_val = fast_tanh(t);
            if (w == 7) {
                huF[lane] = hu_val;
                split2(hu_val, huH[lane], huL[lane]);
            }
        }
        cur = nxt;
    }
}

extern "C" void kernel_launch(void* const* d_in, const int* in_sizes, int n_in,
                              void* d_out, int out_size, void* d_ws, size_t ws_size,
                              hipStream_t stream) {
    const float* atoms = (const float*)d_in[0];
    const float* adj   = (const float*)d_in[1];
    const int*   left  = (const int*)  d_in[2];
    const int*   right = (const int*)  d_in[3];
    const float* Wfe = (const float*)d_in[6];
    const float* bfe = (const float*)d_in[7];
    const float* Wfv = (const float*)d_in[8];
    const float* bfv = (const float*)d_in[9];
    const float* Wfu = (const float*)d_in[10];
    const float* bfu = (const float*)d_in[11];
    const float* Wpe = (const float*)d_in[12];
    const float* bpe = (const float*)d_in[13];
    const float* Wpv = (const float*)d_in[14];
    const float* bpv = (const float*)d_in[15];
    const float* Wpu = (const float*)d_in[16];
    const float* bpu = (const float*)d_in[17];

    graphnet_kernel<<<dim3(NMOLS), dim3(512), 0, stream>>>(
        atoms, adj, left, right,
        Wfe, bfe, Wfv, bfv, Wfu, bfu,
        Wpe, bpe, Wpv, bpv, Wpu, bpu,
        (float*)d_out);
}

// Round 5
// 42.220 us; speedup vs baseline: 2.7435x; 1.2002x over previous
//
#include <hip/hip_runtime.h>

#define NATOMS 8192
#define NMOLS  256
#define APM    32
#define EPM    61
#define D      64
#define FIN    16
#define SE     72   // bf16 elems per LDS state row (144B)

typedef __bf16 bf16x8 __attribute__((ext_vector_type(8)));
typedef float  f32x4  __attribute__((ext_vector_type(4)));

#define MFMA_BF16(a, b, c) __builtin_amdgcn_mfma_f32_16x16x32_bf16((a), (b), (c), 0, 0, 0)

__device__ __forceinline__ ushort f2bf(float x) {   // RNE f32 -> bf16
    uint u = __float_as_uint(x);
    u += 0x7fffu + ((u >> 16) & 1u);
    return (ushort)(u >> 16);
}
__device__ __forceinline__ float bf2f(ushort h) {
    return __uint_as_float(((uint)h) << 16);
}
__device__ __forceinline__ void split2(float x, ushort& h, ushort& l) {
    ushort hh = f2bf(x);
    h = hh;
    l = f2bf(x - bf2f(hh));
}
// tanh(x) = 1 - 2/(exp(2x)+1); exp2-based, saturates correctly at +-inf
__device__ __forceinline__ float fast_tanh(float x) {
    float e = __builtin_amdgcn_exp2f(x * 2.885390081777926f);   // exp(2x)
    float r = __builtin_amdgcn_rcpf(e + 1.0f);
    return __builtin_fmaf(-2.0f, r, 1.0f);
}

union FragU { ushort u[8]; bf16x8 v; };

// split-bf16 3-MFMA step: accH += Ah*Wh ; accL += Al*Wh + Ah*Wl
__device__ __forceinline__ void mfma3(const ushort* pH, const ushort* pL, int o,
                                      bf16x8 wH, bf16x8 wL,
                                      f32x4& accH, f32x4& accL) {
    bf16x8 ah = *(const bf16x8*)(pH + o);
    bf16x8 al = *(const bf16x8*)(pL + o);
    accH = MFMA_BF16(ah, wH, accH);
    accL = MFMA_BF16(al, wH, accL);
    accL = MFMA_BF16(ah, wL, accL);
}

__global__ __launch_bounds__(512, 2) void graphnet_kernel(
    const float* __restrict__ atoms,
    const float* __restrict__ adj,
    const int*   __restrict__ left,
    const int*   __restrict__ right,
    const float* __restrict__ Wfe, const float* __restrict__ bfe,
    const float* __restrict__ Wfv, const float* __restrict__ bfv,
    const float* __restrict__ Wfu, const float* __restrict__ bfu,
    const float* __restrict__ Wpe, const float* __restrict__ bpe,
    const float* __restrict__ Wpv, const float* __restrict__ bpv,
    const float* __restrict__ Wpu, const float* __restrict__ bpu,
    float* __restrict__ out)
{
    __shared__ __align__(16) ushort heH[2][64 * SE], heL[2][64 * SE];  // dbuf; rows 61-63 zero
    __shared__ __align__(16) ushort he0H[64 * SE], he0L[64 * SE];
    __shared__ __align__(16) ushort hvH[2][APM * SE], hvL[2][APM * SE];
    __shared__ __align__(16) ushort hv0H[APM * SE], hv0L[APM * SE];
    __shared__ __align__(16) ushort huH[D], huL[D];
    __shared__ float huF[D], hu0F[D];
    __shared__ float atoms_s[APM * FIN];
    __shared__ float apm_s[FIN];
    __shared__ float bo_s[EPM];
    __shared__ float parte[4][D];
    __shared__ float part2[2][D];
    __shared__ float hebar[D];
    __shared__ float phiu_part[8][D];
    __shared__ int   lloc[EPM], rloc[EPM];
    __shared__ int   inc[APM][4];              // padded with edge 63 (zero row)

    const int tid  = threadIdx.x;
    const int lane = tid & 63;
    const int w    = tid >> 6;                 // wave 0..7
    const int nt   = w & 3;                    // N-tile (16-col slice)
    const int mt2  = w >> 2;                   // 0..1
    const int cb   = __builtin_amdgcn_readfirstlane(nt) * 16;
    const int lr   = lane & 15;
    const int kb   = lane >> 4;
    const int m    = blockIdx.x;

    // ---------------- stage inputs ----------------
    if (tid < EPM) {
        int gl = left [m * EPM + tid];
        int gr = right[m * EPM + tid];
        lloc[tid] = gl - m * APM;
        rloc[tid] = gr - m * APM;
        bo_s[tid] = adj[(size_t)gl * NATOMS + gr];
    }
    if (tid < APM * FIN) atoms_s[tid] = atoms[(size_t)m * (APM * FIN) + tid];

    // ---------------- weight fragments (registers, reused all iters) ----------------
    FragU feH[8], feL[8], fvH[8], fvL[8];
    #pragma unroll
    for (int s = 0; s < 8; ++s) {
        #pragma unroll
        for (int j = 0; j < 8; ++j) {
            split2(Wpe[(s * 32 + kb * 8 + j) * D + cb + lr], feH[s].u[j], feL[s].u[j]);
            split2(Wpv[(s * 32 + kb * 8 + j) * D + cb + lr], fvH[s].u[j], fvL[s].u[j]);
        }
    }
    float wpu_reg[32];
    #pragma unroll
    for (int kk = 0; kk < 32; ++kk)
        wpu_reg[kk] = Wpu[(w * 32 + kk) * D + lane];
    const float bias_e = bpe[cb + lr];
    const float w5_e   = Wpe[4 * D * D + cb + lr];
    const float bias_v = bpv[cb + lr];
    const float bpu_l  = bpu[lane];

    __syncthreads();                                               // B1

    // incidence lists, padded to 4 with zero-row 63 (branchless phi_v)
    if (tid < APM) {
        int dg = 0;
        for (int e = 0; e < EPM; ++e) {
            if (lloc[e] == tid) inc[tid][dg++] = e;
            if (rloc[e] == tid) inc[tid][dg++] = e;
        }
        for (int j = dg; j < 4; ++j) inc[tid][j] = 63;
    }
    if (tid < FIN) {
        float s = 0.f;
        for (int a = 0; a < APM; ++a) s += atoms_s[a * FIN + tid];
        apm_s[tid] = s;
    }
    // h_v init
    #pragma unroll
    for (int i = 0; i < 4; ++i) {
        int idx = tid + 512 * i;               // 0..2047
        int a = idx >> 6, c = idx & 63;
        float acc = bfv[c];
        #pragma unroll
        for (int f = 0; f < FIN; ++f) acc += atoms_s[a * FIN + f] * Wfv[f * D + c];
        float t = fast_tanh(acc);
        ushort h, l; split2(t, h, l);
        hvH[0][a * SE + c] = h; hvL[0][a * SE + c] = l;
        hv0H[a * SE + c] = h;   hv0L[a * SE + c] = l;
    }
    // h_e init (+ zero pad rows 61..63 in BOTH buffers, never rewritten)
    #pragma unroll
    for (int i = 0; i < 8; ++i) {
        int idx = tid + 512 * i;               // 0..4095
        int e = idx >> 6, c = idx & 63;
        float t = 0.f;
        if (e < EPM) t = fast_tanh(bo_s[e] * Wfe[c] + bfe[c]);
        ushort h, l; split2(t, h, l);
        heH[0][e * SE + c] = h; heL[0][e * SE + c] = l;
        he0H[e * SE + c] = h;   he0L[e * SE + c] = l;
        if (e >= EPM) { heH[1][e * SE + c] = 0; heL[1][e * SE + c] = 0; }
    }
    __syncthreads();                                               // B2

    // h_u: redundantly in registers per wave (lane = feature)
    float hu_val;
    {
        float acc = bfu[lane];
        #pragma unroll
        for (int f = 0; f < FIN; ++f) acc += apm_s[f] * Wfu[f * D + lane];
        hu_val = fast_tanh(acc);
        if (w == 7) {
            huF[lane] = hu_val; hu0F[lane] = hu_val;
            split2(hu_val, huH[lane], huL[lane]);
        }
    }

    const int col  = cb + lr;
    const int e0   = mt2 * 16 + lr;
    const int e1   = e0 + 32;
    const int ec1  = (e1 < EPM) ? e1 : EPM - 1;
    const int la0  = lloc[e0],  ra0 = rloc[e0];
    const int la1  = lloc[ec1], ra1 = rloc[ec1];
    const int ofk  = kb * 8;
    const int arow = mt2 * 16 + lr;

    int cur = 0;
    // ---------------- 3 message-passing iterations, 3 barriers each ----------------
    for (int it = 0; it < 3; ++it) {
        const ushort* heHc = heH[cur]; const ushort* heLc = heL[cur];
        const ushort* hvHc = hvH[cur]; const ushort* hvLc = hvL[cur];

        // ---- phi_e MFMA chain (48 MFMA) — issued BEFORE hu finalize ----
        f32x4 aH0 = {0,0,0,0}, aL0 = {0,0,0,0}, aH1 = {0,0,0,0}, aL1 = {0,0,0,0};
        mfma3(heHc + e0*SE,  heLc + e0*SE,  ofk,      feH[0].v, feL[0].v, aH0, aL0);
        mfma3(heHc + e1*SE,  heLc + e1*SE,  ofk,      feH[0].v, feL[0].v, aH1, aL1);
        mfma3(heHc + e0*SE,  heLc + e0*SE,  32 + ofk, feH[1].v, feL[1].v, aH0, aL0);
        mfma3(heHc + e1*SE,  heLc + e1*SE,  32 + ofk, feH[1].v, feL[1].v, aH1, aL1);
        mfma3(he0H + e0*SE,  he0L + e0*SE,  ofk,      feH[2].v, feL[2].v, aH0, aL0);
        mfma3(he0H + e1*SE,  he0L + e1*SE,  ofk,      feH[2].v, feL[2].v, aH1, aL1);
        mfma3(he0H + e0*SE,  he0L + e0*SE,  32 + ofk, feH[3].v, feL[3].v, aH0, aL0);
        mfma3(he0H + e1*SE,  he0L + e1*SE,  32 + ofk, feH[3].v, feL[3].v, aH1, aL1);
        mfma3(hvHc + la0*SE, hvLc + la0*SE, ofk,      feH[4].v, feL[4].v, aH0, aL0);
        mfma3(hvHc + la1*SE, hvLc + la1*SE, ofk,      feH[4].v, feL[4].v, aH1, aL1);
        mfma3(hvHc + la0*SE, hvLc + la0*SE, 32 + ofk, feH[5].v, feL[5].v, aH0, aL0);
        mfma3(hvHc + la1*SE, hvLc + la1*SE, 32 + ofk, feH[5].v, feL[5].v, aH1, aL1);
        mfma3(hvHc + ra0*SE, hvLc + ra0*SE, ofk,      feH[6].v, feL[6].v, aH0, aL0);
        mfma3(hvHc + ra1*SE, hvLc + ra1*SE, ofk,      feH[6].v, feL[6].v, aH1, aL1);
        mfma3(hvHc + ra0*SE, hvLc + ra0*SE, 32 + ofk, feH[7].v, feL[7].v, aH0, aL0);
        mfma3(hvHc + ra1*SE, hvLc + ra1*SE, 32 + ofk, feH[7].v, feL[7].v, aH1, aL1);

        // ---- deferred hu finalize (reads phiu_part, D-guarded from prev iter),
        //      hidden under the MFMA latency above ----
        if (it > 0) {
            float t = bpu_l;
            #pragma unroll
            for (int w8 = 0; w8 < 8; ++w8) t += phiu_part[w8][lane];
            hu_val = fast_tanh(t);
            if (w == 7) {
                huF[lane] = hu_val;
                split2(hu_val, huH[lane], huL[lane]);
            }
        }
        // u_e = sum(h_u): register butterfly
        float uev = hu_val;
        #pragma unroll
        for (int off = 32; off; off >>= 1) uev += __shfl_xor(uev, off, 64);

        // ---- phi_e epilogue ----
        float out0[4], out1[4]; float ps0 = 0.f, ps1 = 0.f;
        #pragma unroll
        for (int r = 0; r < 4; ++r) {
            float t0 = fast_tanh(aH0[r] + aL0[r] + bias_e + uev * w5_e);
            float t1 = fast_tanh(aH1[r] + aL1[r] + bias_e + uev * w5_e);
            out0[r] = t0; out1[r] = t1;
            ps0 += t0;
            if (32 + mt2 * 16 + kb * 4 + r < EPM) ps1 += t1;
        }

        if (it == 2) {                         // final: write output, done
            #pragma unroll
            for (int r = 0; r < 4; ++r) {
                int g0 = mt2 * 16 + kb * 4 + r;
                out[((size_t)(m * EPM + g0)) * D + col] = out0[r];
                int g1 = g0 + 32;
                if (g1 < EPM) out[((size_t)(m * EPM + g1)) * D + col] = out1[r];
            }
            return;
        }

        ps0 += __shfl_xor(ps0, 16, 64); ps0 += __shfl_xor(ps0, 32, 64);
        ps1 += __shfl_xor(ps1, 16, 64); ps1 += __shfl_xor(ps1, 32, 64);

        const int nxt = cur ^ 1;
        #pragma unroll
        for (int r = 0; r < 4; ++r) {
            int g0 = mt2 * 16 + kb * 4 + r;
            split2(out0[r], heH[nxt][g0 * SE + col], heL[nxt][g0 * SE + col]);
            int g1 = g0 + 32;
            if (g1 < EPM)
                split2(out1[r], heH[nxt][g1 * SE + col], heL[nxt][g1 * SE + col]);
        }
        if (kb == 0) { parte[mt2][col] = ps0; parte[2 + mt2][col] = ps1; }
        __syncthreads();                                           // A: new he ready

        if (tid < D)   // hebar reduce (readers are post-C)
            hebar[tid] = parte[0][tid] + parte[1][tid] + parte[2][tid] + parte[3][tid];

        // ---- phi_v: inline hbi via MFMA linearity (42 MFMA, no scatter pass) ----
        const ushort* heHn = heH[nxt]; const ushort* heLn = heL[nxt];
        const int ie0 = inc[arow][0], ie1 = inc[arow][1];
        const int ie2 = inc[arow][2], ie3 = inc[arow][3];

        f32x4 vH = {0,0,0,0}, vL = {0,0,0,0};
        mfma3(hvHc + arow*SE, hvLc + arow*SE, ofk,      fvH[0].v, fvL[0].v, vH, vL);
        mfma3(hvHc + arow*SE, hvLc + arow*SE, 32 + ofk, fvH[1].v, fvL[1].v, vH, vL);
        mfma3(hv0H + arow*SE, hv0L + arow*SE, ofk,      fvH[2].v, fvL[2].v, vH, vL);
        mfma3(hv0H + arow*SE, hv0L + arow*SE, 32 + ofk, fvH[3].v, fvL[3].v, vH, vL);
        // hbi = sum of 4 incident edges (pads hit zero-row 63): feed each directly
        mfma3(heHn + ie0*SE, heLn + ie0*SE, ofk,      fvH[4].v, fvL[4].v, vH, vL);
        mfma3(heHn + ie0*SE, heLn + ie0*SE, 32 + ofk, fvH[5].v, fvL[5].v, vH, vL);
        mfma3(heHn + ie1*SE, heLn + ie1*SE, ofk,      fvH[4].v, fvL[4].v, vH, vL);
        mfma3(heHn + ie1*SE, heLn + ie1*SE, 32 + ofk, fvH[5].v, fvL[5].v, vH, vL);
        mfma3(heHn + ie2*SE, heLn + ie2*SE, ofk,      fvH[4].v, fvL[4].v, vH, vL);
        mfma3(heHn + ie2*SE, heLn + ie2*SE, 32 + ofk, fvH[5].v, fvL[5].v, vH, vL);
        mfma3(heHn + ie3*SE, heLn + ie3*SE, ofk,      fvH[4].v, fvL[4].v, vH, vL);
        mfma3(heHn + ie3*SE, heLn + ie3*SE, 32 + ofk, fvH[5].v, fvL[5].v, vH, vL);
        // u_v broadcast row
        mfma3(huH, huL, ofk,      fvH[6].v, fvL[6].v, vH, vL);
        mfma3(huH, huL, 32 + ofk, fvH[7].v, fvL[7].v, vH, vL);

        float outv2[4]; float ps2 = 0.f;
        #pragma unroll
        for (int r = 0; r < 4; ++r) {
            float t = fast_tanh(vH[r] + vL[r] + bias_v);
            outv2[r] = t; ps2 += t;
        }
        ps2 += __shfl_xor(ps2, 16, 64); ps2 += __shfl_xor(ps2, 32, 64);
        #pragma unroll
        for (int r = 0; r < 4; ++r) {
            int g = mt2 * 16 + kb * 4 + r;
            split2(outv2[r], hvH[nxt][g * SE + col], hvL[nxt][g * SE + col]);
        }
        if (kb == 0) part2[mt2][col] = ps2;
        __syncthreads();                                           // C: hv' + part2 ready

        // ---- phi_u partials: wave w owns K rows [w*32, w*32+32) ----
        {
            const int b  = w >> 1;             // source block (wave-uniform)
            const int k0 = (w & 1) * 32;
            float s = 0.f;
            #pragma unroll
            for (int kk = 0; kk < 32; ++kk) {
                int k = k0 + kk;
                float x = (b == 0) ? huF[k] : (b == 1) ? hu0F[k]
                        : (b == 2) ? hebar[k] : (part2[0][k] + part2[1][k]);
                s += x * wpu_reg[kk];
            }
            phiu_part[w][lane] = s;
        }
        __syncthreads();                                           // D: phiu_part ready
        cur = nxt;                             // hu finalize deferred to next iter
    }
}

extern "C" void kernel_launch(void* const* d_in, const int* in_sizes, int n_in,
                              void* d_out, int out_size, void* d_ws, size_t ws_size,
                              hipStream_t stream) {
    const float* atoms = (const float*)d_in[0];
    const float* adj   = (const float*)d_in[1];
    const int*   left  = (const int*)  d_in[2];
    const int*   right = (const int*)  d_in[3];
    const float* Wfe = (const float*)d_in[6];
    const float* bfe = (const float*)d_in[7];
    const float* Wfv = (const float*)d_in[8];
    const float* bfv = (const float*)d_in[9];
    const float* Wfu = (const float*)d_in[10];
    const float* bfu = (const float*)d_in[11];
    const float* Wpe = (const float*)d_in[12];
    const float* bpe = (const float*)d_in[13];
    const float* Wpv = (const float*)d_in[14];
    const float* bpv = (const float*)d_in[15];
    const float* Wpu = (const float*)d_in[16];
    const float* bpu = (const float*)d_in[17];

    graphnet_kernel<<<dim3(NMOLS), dim3(512), 0, stream>>>(
        atoms, adj, left, right,
        Wfe, bfe, Wfv, bfv, Wfu, bfu,
        Wpe, bpe, Wpv, bpv, Wpu, bpu,
        (float*)d_out);
}